// Round 11
// baseline (579.022 us; speedup 1.0000x reference)
//
#include <hip/hip_runtime.h>

typedef float  f32x4 __attribute__((ext_vector_type(4)));
typedef _Float16 half8 __attribute__((ext_vector_type(8)));

#define BN_EPS 1e-5f
#define NGRAPH 64

// ---------------------------------------------------------------- weights prep
struct PrepArgs {
    const float* src[8];
    _Float16*    dst[8];
    int          K[8];
};

__global__ void prep_weights(PrepArgs a) {
    int m = blockIdx.y;
    int K = a.K[m];
    int total = K << 8;
    int idx = blockIdx.x * blockDim.x + threadIdx.x;
    if (idx >= total) return;
    int n = idx / K;
    int k = idx - n * K;
    a.dst[m][idx] = (_Float16)a.src[m][(size_t)k * 256 + n];
}

__global__ void cast_x(const float* __restrict__ x, _Float16* __restrict__ o, int total) {
    int i = (blockIdx.x * blockDim.x + threadIdx.x) << 3;
    if (i >= total) return;
    f32x4 a = *(const f32x4*)(x + i);
    f32x4 b = *(const f32x4*)(x + i + 4);
    half8 r;
#pragma unroll
    for (int k = 0; k < 4; ++k) { r[k] = (_Float16)a[k]; r[k + 4] = (_Float16)b[k]; }
    *(half8*)(o + i) = r;
}

// ---------------------------------------------------------------- CSR build
__global__ void edge_count(const int* __restrict__ ei, int* __restrict__ cnt,
                           int* __restrict__ rank, int E) {
    int e = blockIdx.x * blockDim.x + threadIdx.x;
    if (e < E) rank[e] = atomicAdd(&cnt[ei[E + e]], 1);
}

__global__ void scan_p1(const int* __restrict__ cnt, int* __restrict__ part, int N) {
    __shared__ int lds[256];
    int idx = blockIdx.x * 256 + threadIdx.x;
    lds[threadIdx.x] = (idx < N) ? cnt[idx] : 0;
    __syncthreads();
    for (int d = 128; d > 0; d >>= 1) {
        if (threadIdx.x < d) lds[threadIdx.x] += lds[threadIdx.x + d];
        __syncthreads();
    }
    if (threadIdx.x == 0) part[blockIdx.x] = lds[0];
}

__global__ void scan_p2(int* __restrict__ part, int* __restrict__ off, int N, int nb) {
    __shared__ int lds[256];
    int t = threadIdx.x;
    int v = (t < nb) ? part[t] : 0;
    lds[t] = v;
    __syncthreads();
    for (int d = 1; d < 256; d <<= 1) {
        int a = (t >= d) ? lds[t - d] : 0;
        __syncthreads();
        lds[t] += a;
        __syncthreads();
    }
    if (t < nb) part[t] = lds[t] - v;
    if (t == nb - 1) off[N] = lds[t];
}

__global__ void scan_p3(const int* __restrict__ cnt, const int* __restrict__ part,
                        int* __restrict__ off, int N) {
    __shared__ int lds[256];
    int t = threadIdx.x;
    int idx = blockIdx.x * 256 + t;
    int v = (idx < N) ? cnt[idx] : 0;
    lds[t] = v;
    __syncthreads();
    for (int d = 1; d < 256; d <<= 1) {
        int a = (t >= d) ? lds[t - d] : 0;
        __syncthreads();
        lds[t] += a;
        __syncthreads();
    }
    if (idx < N) off[idx] = part[blockIdx.x] + lds[t] - v;
}

__global__ void edge_fill(const int* __restrict__ ei, const int* __restrict__ off,
                          const int* __restrict__ rank, int* __restrict__ csr_src, int E) {
    int e = blockIdx.x * blockDim.x + threadIdx.x;
    if (e >= E) return;
    csr_src[off[ei[E + e]] + rank[e]] = ei[e];
}

// ---------------------------------------------------------------- BN coefs
__global__ void bn_coef(const float* __restrict__ stats, const float* __restrict__ gam,
                        const float* __restrict__ bet, _Float16* __restrict__ c16,
                        float* __restrict__ c32, float invN) {
    int c = threadIdx.x;
    float mu = stats[c] * invN;
    float var = stats[256 + c] * invN - mu * mu;
    float s = gam[c] * rsqrtf(var + BN_EPS);
    float t = bet[c] - mu * s;
    c16[c] = (_Float16)s; c16[256 + c] = (_Float16)t;
    c32[c] = s; c32[256 + c] = t;
}

// ---------------------------------------------------------------- gathers
// (HBM random-read bound at ~185MB compulsory traffic — at structural floor)
__global__ void gather0(const _Float16* __restrict__ x, const int* __restrict__ off,
                        const int* __restrict__ srcs, _Float16* __restrict__ out, int N) {
    int wid = (blockIdx.x << 2) + (threadIdx.x >> 6);
    if (wid >= N) return;
    int lane = threadIdx.x & 63;
    int q = lane >> 4;
    int fb = (lane & 15) << 3;
    const char* xb = (const char*)x;
    unsigned fb2 = (unsigned)fb << 1;
    float acc[8] = {0.f, 0.f, 0.f, 0.f, 0.f, 0.f, 0.f, 0.f};
    int end = off[wid + 1];
    int e = off[wid] + q;
    for (; e + 4 < end; e += 8) {
        half8 v0 = *(const half8*)(xb + (((unsigned)srcs[e] << 8) + fb2));
        half8 v1 = *(const half8*)(xb + (((unsigned)srcs[e + 4] << 8) + fb2));
        half8 p = v0 + v1;
#pragma unroll
        for (int k = 0; k < 8; ++k) acc[k] += (float)p[k];
    }
    if (e < end) {
        half8 v0 = *(const half8*)(xb + (((unsigned)srcs[e] << 8) + fb2));
#pragma unroll
        for (int k = 0; k < 8; ++k) acc[k] += (float)v0[k];
    }
    if (q == 0) {
        half8 v = *(const half8*)(xb + (((unsigned)wid << 8) + fb2));
#pragma unroll
        for (int k = 0; k < 8; ++k) acc[k] += (float)v[k];
    }
#pragma unroll
    for (int k = 0; k < 8; ++k) {
        acc[k] += __shfl_xor(acc[k], 16);
        acc[k] += __shfl_xor(acc[k], 32);
    }
    if (q == 0) {
        half8 o;
#pragma unroll
        for (int k = 0; k < 8; ++k) o[k] = (_Float16)acc[k];
        *(half8*)(out + (size_t)wid * 128 + fb) = o;
    }
}

__global__ void gather_fused(const _Float16* __restrict__ z, const int* __restrict__ off,
                             const int* __restrict__ srcs, const _Float16* __restrict__ coef,
                             _Float16* __restrict__ out, int N) {
    int wid = (blockIdx.x << 2) + (threadIdx.x >> 6);
    if (wid >= N) return;
    int lane = threadIdx.x & 63;
    int hf = lane >> 5;
    int fb = (lane & 31) << 3;
    half8 sc8 = *(const half8*)(coef + fb);
    half8 tc8 = *(const half8*)(coef + 256 + fb);
    const half8 zero8 = {0, 0, 0, 0, 0, 0, 0, 0};
    const char* zb = (const char*)z;
    unsigned fb2 = (unsigned)fb << 1;
    float acc[8] = {0.f, 0.f, 0.f, 0.f, 0.f, 0.f, 0.f, 0.f};
    int end = off[wid + 1];
    int e = off[wid] + hf;
    for (; e + 6 < end; e += 8) {
        half8 v0 = *(const half8*)(zb + (((unsigned)srcs[e] << 9) + fb2));
        half8 v1 = *(const half8*)(zb + (((unsigned)srcs[e + 2] << 9) + fb2));
        half8 v2 = *(const half8*)(zb + (((unsigned)srcs[e + 4] << 9) + fb2));
        half8 v3 = *(const half8*)(zb + (((unsigned)srcs[e + 6] << 9) + fb2));
        half8 r0 = __builtin_elementwise_max(v0 * sc8 + tc8, zero8);
        half8 r1 = __builtin_elementwise_max(v1 * sc8 + tc8, zero8);
        half8 r2 = __builtin_elementwise_max(v2 * sc8 + tc8, zero8);
        half8 r3 = __builtin_elementwise_max(v3 * sc8 + tc8, zero8);
        half8 p01 = r0 + r1;
        half8 p23 = r2 + r3;
#pragma unroll
        for (int k = 0; k < 8; ++k)
            acc[k] += (float)p01[k] + (float)p23[k];
    }
    for (; e < end; e += 2) {
        half8 v0 = *(const half8*)(zb + (((unsigned)srcs[e] << 9) + fb2));
        half8 r0 = __builtin_elementwise_max(v0 * sc8 + tc8, zero8);
#pragma unroll
        for (int k = 0; k < 8; ++k) acc[k] += (float)r0[k];
    }
    if (hf == 0) {
        half8 v = *(const half8*)(zb + (((unsigned)wid << 9) + fb2));
        half8 r = __builtin_elementwise_max(v * sc8 + tc8, zero8);
#pragma unroll
        for (int k = 0; k < 8; ++k) acc[k] += (float)r[k];
    }
#pragma unroll
    for (int k = 0; k < 8; ++k) acc[k] += __shfl_xor(acc[k], 32);
    if (hf == 0) {
        half8 o;
#pragma unroll
        for (int k = 0; k < 8; ++k) o[k] = (_Float16)acc[k];
        *(half8*)(out + (size_t)wid * 256 + fb) = o;
    }
}

// ---------------------------------------------------------------- fused MLP v2
// 64-row blocks (4 waves x 16 rows), 256 threads. LDS 72KB -> 2 blocks/CU
// (fixes r5's 1-block/CU stall). BOTH weight matrices K-chunk staged through
// LDS (fixes r5's global-streamed W2). y lives only in LDS (XOR-swizzled),
// read back as stage-2 A-fragments. Saves the 51MB/layer y round-trip.
// Epilogue: block-reduced BN stats + two-phase LDS-staged coalesced z store.
template <int K1>
__global__ __launch_bounds__(256, 2) void mlp2(
    const _Float16* __restrict__ A, const _Float16* __restrict__ W1T,
    const float* __restrict__ b1, const _Float16* __restrict__ W2T,
    const float* __restrict__ b2, _Float16* __restrict__ Z,
    float* __restrict__ stats, int M) {
    extern __shared__ _Float16 lds[];
    _Float16* Wr = lds;                      // [256 cols][64 k] swizzled, 32KB
    _Float16* Yr = lds + 16384;              // [64 rows][256 cols] swizzled, 32KB
    float* sred = (float*)(lds + 32768);     // [2][4 waves][256 cols], 8KB
    const int tid = threadIdx.x;
    const int lane = tid & 63, wave = tid >> 6;
    const int i = lane & 15, g = lane >> 4;
    const int rowbase = blockIdx.x * 64 + wave * 16;
    const int arow = min(rowbase + i, M - 1);
    const int swi = (i & 7) << 3;
    const int ssw = (tid & 7) << 3;

    half8 af[K1 / 32];
#pragma unroll
    for (int s = 0; s < K1 / 32; ++s)
        af[s] = *(const half8*)(A + (size_t)arow * K1 + s * 32 + g * 8);

    f32x4 acc[16];
#pragma unroll
    for (int t = 0; t < 16; ++t) acc[t] = (f32x4){0.f, 0.f, 0.f, 0.f};

    // ---- stage 1: y = A @ W1
#pragma unroll
    for (int kc = 0; kc < K1 / 64; ++kc) {
        if (kc) __syncthreads();
        {   // stage [256][64] chunk: thread tid = one col, 8 x half8
            const _Float16* src = W1T + (size_t)tid * K1 + kc * 64;
            _Float16* dst = Wr + tid * 64;
#pragma unroll
            for (int c = 0; c < 64; c += 8)
                *(half8*)(dst + (c ^ ssw)) = *(const half8*)(src + c);
        }
        __syncthreads();
#pragma unroll
        for (int ks = 0; ks < 2; ++ks)
#pragma unroll
            for (int t = 0; t < 16; ++t) {
                half8 b = *(const half8*)(Wr + (t * 16 + i) * 64 + ((ks * 32 + g * 8) ^ swi));
                acc[t] = __builtin_amdgcn_mfma_f32_16x16x32_f16(af[kc * 2 + ks], b, acc[t], 0, 0, 0);
            }
    }

    // y = relu(acc + b1) -> Yr, row-keyed XOR swizzle
    const int rg = g * 4;
#pragma unroll
    for (int t = 0; t < 16; ++t) {
        int c = t * 16 + i;
        float bv = b1[c];
#pragma unroll
        for (int j = 0; j < 4; ++j) {
            int r = wave * 16 + rg + j;
            Yr[r * 256 + (c ^ ((r & 7) << 3))] = (_Float16)fmaxf(acc[t][j] + bv, 0.f);
        }
    }
    __syncthreads();                          // Yr complete; stage-1 Wr reads done

    // stage-2 A fragments from LDS y (row = wave*16+i, swizzle key == swi)
    half8 af2[8];
#pragma unroll
    for (int s = 0; s < 8; ++s)
        af2[s] = *(const half8*)(Yr + (wave * 16 + i) * 256 + ((s * 32 + g * 8) ^ swi));

#pragma unroll
    for (int t = 0; t < 16; ++t) acc[t] = (f32x4){0.f, 0.f, 0.f, 0.f};

    // ---- stage 2: z = y @ W2
#pragma unroll
    for (int kc = 0; kc < 4; ++kc) {
        if (kc) __syncthreads();
        {
            const _Float16* src = W2T + (size_t)tid * 256 + kc * 64;
            _Float16* dst = Wr + tid * 64;
#pragma unroll
            for (int c = 0; c < 64; c += 8)
                *(half8*)(dst + (c ^ ssw)) = *(const half8*)(src + c);
        }
        __syncthreads();
#pragma unroll
        for (int ks = 0; ks < 2; ++ks)
#pragma unroll
            for (int t = 0; t < 16; ++t) {
                half8 b = *(const half8*)(Wr + (t * 16 + i) * 64 + ((ks * 32 + g * 8) ^ swi));
                acc[t] = __builtin_amdgcn_mfma_f32_16x16x32_f16(af2[kc * 2 + ks], b, acc[t], 0, 0, 0);
            }
    }

    // ---- BN stats (block-reduced, 1 atomic/col for each of sum/sumsq)
#pragma unroll
    for (int t = 0; t < 16; ++t) {
        int c = t * 16 + i;
        float bv = b2[c];
        float s1 = 0.f, s2 = 0.f;
#pragma unroll
        for (int j = 0; j < 4; ++j) {
            if (rowbase + rg + j < M) {
                float v = acc[t][j] + bv;
                s1 += v;
                s2 += v * v;
            }
        }
        s1 += __shfl_xor(s1, 16); s1 += __shfl_xor(s1, 32);
        s2 += __shfl_xor(s2, 16); s2 += __shfl_xor(s2, 32);
        if (g == 0) {
            sred[wave * 256 + c] = s1;
            sred[1024 + wave * 256 + c] = s2;
        }
    }
    __syncthreads();                          // sred ready; all Wr reads done
    {
        float ss1 = 0.f, ss2 = 0.f;
#pragma unroll
        for (int w = 0; w < 4; ++w) {
            ss1 += sred[w * 256 + tid];
            ss2 += sred[1024 + w * 256 + tid];
        }
        atomicAdd(&stats[tid], ss1);
        atomicAdd(&stats[256 + tid], ss2);
    }

    // ---- two-phase coalesced z store via ostage [64][136] (reuses Wr region)
    _Float16* ostage = lds;
#pragma unroll
    for (int ph = 0; ph < 2; ++ph) {
        if (ph) __syncthreads();
#pragma unroll
        for (int tt = 0; tt < 8; ++tt) {
            int t = ph * 8 + tt;
            int lc = tt * 16 + i;
            float bv = b2[t * 16 + i];
#pragma unroll
            for (int j = 0; j < 4; ++j)
                ostage[(wave * 16 + rg + j) * 136 + lc] = (_Float16)(acc[t][j] + bv);
        }
        __syncthreads();
#pragma unroll
        for (int k = 0; k < 4; ++k) {
            int ch = k * 256 + tid;
            int rl = ch >> 4, pc = (ch & 15) << 3;
            int r = blockIdx.x * 64 + rl;
            if (r < M)
                *(half8*)(Z + (size_t)r * 256 + ph * 128 + pc) =
                    *(const half8*)(ostage + rl * 136 + pc);
        }
    }
}

// ---------------------------------------------------------------- pooling
__global__ void graph_bounds(const int* __restrict__ batch, int* __restrict__ gstart, int N) {
    int t = threadIdx.x;
    if (t > NGRAPH) return;
    if (t == NGRAPH) { gstart[t] = N; return; }
    int lo = 0, hi = N;
    while (lo < hi) { int m = (lo + hi) >> 1; if (batch[m] < t) lo = m + 1; else hi = m; }
    gstart[t] = lo;
}

#define PCHUNK 256
__global__ void pool_stage1(const _Float16* __restrict__ z, const int* __restrict__ batch,
                            const int* __restrict__ gstart, const float* __restrict__ c32,
                            float* __restrict__ acc, int N) {
    __shared__ float lds[8 * 512];
    int c0 = blockIdx.x * PCHUNK;
    int cend = min(c0 + PCHUNK, N);
    int tid = threadIdx.x;
    int rowlane = tid >> 5;
    int fb = (tid & 31) << 3;
    float sc[8], tc[8];
#pragma unroll
    for (int k = 0; k < 8; ++k) { sc[k] = c32[fb + k]; tc[k] = c32[256 + fb + k]; }
    int segs = c0;
    while (segs < cend) {
        int g = batch[segs];
        int sege = min(gstart[g + 1], cend);
        float a[8] = {0.f, 0.f, 0.f, 0.f, 0.f, 0.f, 0.f, 0.f};
        for (int r = segs + rowlane; r < sege; r += 16) {
            half8 v = *(const half8*)(z + (size_t)r * 256 + fb);
#pragma unroll
            for (int k = 0; k < 8; ++k)
                a[k] += fmaxf(fmaf((float)v[k], sc[k], tc[k]), 0.f);
        }
#pragma unroll
        for (int k = 0; k < 8; ++k) lds[k * 512 + tid] = a[k];
        __syncthreads();
#pragma unroll
        for (int d = 8; d > 0; d >>= 1) {
            if (rowlane < d) {
#pragma unroll
                for (int k = 0; k < 8; ++k)
                    lds[k * 512 + tid] += lds[k * 512 + tid + d * 32];
            }
            __syncthreads();
        }
        if (rowlane == 0) {
#pragma unroll
            for (int k = 0; k < 8; ++k)
                atomicAdd(&acc[g * 256 + fb + k], lds[k * 512 + tid]);
        }
        __syncthreads();
        segs = sege;
    }
}

__global__ void pool_finalize(const float* __restrict__ acc, const int* __restrict__ gstart,
                              float* __restrict__ out) {
    int i = blockIdx.x * 256 + threadIdx.x;
    int g = i >> 8;
    int c = gstart[g + 1] - gstart[g];
    out[i] = acc[i] / (float)(c > 0 ? c : 1);
}

// ---------------------------------------------------------------- launch
extern "C" void kernel_launch(void* const* d_in, const int* in_sizes, int n_in,
                              void* d_out, int out_size, void* d_ws, size_t ws_size,
                              hipStream_t stream) {
    const float* x    = (const float*)d_in[0];
    const int*   ei   = (const int*)d_in[1];
    const int*   batch= (const int*)d_in[2];
    const float* w1_0 = (const float*)d_in[3];
    const float* b1_0 = (const float*)d_in[4];
    const float* w2_0 = (const float*)d_in[5];
    const float* b2_0 = (const float*)d_in[6];
    const float* g_0  = (const float*)d_in[7];
    const float* be_0 = (const float*)d_in[8];
    const float* w1_r = (const float*)d_in[9];
    const float* b1_r = (const float*)d_in[10];
    const float* w2_r = (const float*)d_in[11];
    const float* b2_r = (const float*)d_in[12];
    const float* g_r  = (const float*)d_in[13];
    const float* be_r = (const float*)d_in[14];

    const int N = in_sizes[0] / 128;   // 50000
    const int E = in_sizes[1] / 2;     // 800000

    char* p = (char*)d_ws;
    auto alloc = [&](size_t bytes) { char* r = p; p += (bytes + 255) & ~(size_t)255; return r; };
    float*    stats   = (float*)alloc(4 * 512 * sizeof(float));
    _Float16* coef16  = (_Float16*)alloc(512 * sizeof(_Float16));
    float*    coef32  = (float*)alloc(512 * sizeof(float));
    int*      part    = (int*)alloc(256 * sizeof(int));
    int*      off     = (int*)alloc((size_t)(N + 1) * sizeof(int));
    int*      cnt     = (int*)alloc((size_t)N * sizeof(int));
    int*      gstart  = (int*)alloc(65 * sizeof(int));
    float*    accp    = (float*)alloc(NGRAPH * 256 * sizeof(float));
    int*      rank    = (int*)alloc((size_t)E * sizeof(int));
    int*      csr_src = (int*)alloc((size_t)E * sizeof(int));
    _Float16* wT      = (_Float16*)alloc((size_t)491520 * sizeof(_Float16));
    _Float16* x16     = (_Float16*)alloc((size_t)N * 128 * sizeof(_Float16));
    _Float16* zin     = (_Float16*)alloc((size_t)N * 256 * sizeof(_Float16));
    _Float16* z       = (_Float16*)alloc((size_t)N * 256 * sizeof(_Float16));

    hipMemsetAsync(stats, 0, 4 * 512 * sizeof(float), stream);
    hipMemsetAsync(cnt, 0, (size_t)N * sizeof(int), stream);
    hipMemsetAsync(accp, 0, NGRAPH * 256 * sizeof(float), stream);

    PrepArgs pa;
    pa.src[0] = w1_0;  pa.dst[0] = wT;           pa.K[0] = 128;
    pa.src[1] = w2_0;  pa.dst[1] = wT + 32768;   pa.K[1] = 256;
    for (int i = 0; i < 3; ++i) {
        pa.src[2 + i] = w1_r + (size_t)i * 65536; pa.dst[2 + i] = wT + 98304 + (size_t)i * 65536; pa.K[2 + i] = 256;
        pa.src[5 + i] = w2_r + (size_t)i * 65536; pa.dst[5 + i] = wT + 294912 + (size_t)i * 65536; pa.K[5 + i] = 256;
    }
    prep_weights<<<dim3(256, 8), 256, 0, stream>>>(pa);
    cast_x<<<(N * 128 / 8 + 255) / 256, 256, 0, stream>>>(x, x16, N * 128);

    const int eb = (E + 255) / 256;
    const int nb = (N + 255) / 256;
    edge_count<<<eb, 256, 0, stream>>>(ei, cnt, rank, E);
    scan_p1<<<nb, 256, 0, stream>>>(cnt, part, N);
    scan_p2<<<1, 256, 0, stream>>>(part, off, N, nb);
    scan_p3<<<nb, 256, 0, stream>>>(cnt, part, off, N);
    edge_fill<<<eb, 256, 0, stream>>>(ei, off, rank, csr_src, E);
    graph_bounds<<<1, 128, 0, stream>>>(batch, gstart, N);

    const int gwb  = (N + 3) / 4;
    const int mlpg = (N + 63) / 64;
    const int ldsm = 73728;                    // 32K W + 32K Y + 8K sred
    const float invN = 1.0f / (float)N;

    // ---- layer 0
    gather0<<<gwb, 256, 0, stream>>>(x16, off, csr_src, zin, N);
    mlp2<128><<<mlpg, 256, ldsm, stream>>>(zin, wT, b1_0, wT + 32768, b2_0, z, stats, N);
    bn_coef<<<1, 256, 0, stream>>>(stats, g_0, be_0, coef16, coef32, invN);

    // ---- layers 1..3
    for (int i = 0; i < 3; ++i) {
        gather_fused<<<gwb, 256, 0, stream>>>(z, off, csr_src, coef16, zin, N);
        mlp2<256><<<mlpg, 256, ldsm, stream>>>(
            zin, wT + 98304 + (size_t)i * 65536, b1_r + i * 256,
            wT + 294912 + (size_t)i * 65536, b2_r + i * 256, z, stats + (i + 1) * 512, N);
        bn_coef<<<1, 256, 0, stream>>>(stats + (i + 1) * 512, g_r + i * 256, be_r + i * 256,
                                       coef16, coef32, invN);
    }

    // ---- pool
    pool_stage1<<<(N + PCHUNK - 1) / PCHUNK, 512, 0, stream>>>(
        z, batch, gstart, coef32, accp, N);
    pool_finalize<<<NGRAPH, 256, 0, stream>>>(accp, gstart, (float*)d_out);
}

// Round 12
// 462.165 us; speedup vs baseline: 1.2528x; 1.2528x over previous
//
#include <hip/hip_runtime.h>

typedef float  f32x4 __attribute__((ext_vector_type(4)));
typedef _Float16 half8 __attribute__((ext_vector_type(8)));

#define BN_EPS 1e-5f
#define NGRAPH 64

// ---------------------------------------------------------------- weights prep
struct PrepArgs {
    const float* src[8];
    _Float16*    dst[8];
    int          K[8];
};

__global__ void prep_weights(PrepArgs a) {
    int m = blockIdx.y;
    int K = a.K[m];
    int total = K << 8;
    int idx = blockIdx.x * blockDim.x + threadIdx.x;
    if (idx >= total) return;
    int n = idx / K;
    int k = idx - n * K;
    a.dst[m][idx] = (_Float16)a.src[m][(size_t)k * 256 + n];
}

// cast + zero-init of stats/cnt/accp (replaces 3 memset dispatches)
__global__ void cast_x(const float* __restrict__ x, _Float16* __restrict__ o, int total,
                       float* __restrict__ stats, int* __restrict__ cnt,
                       float* __restrict__ accp, int N) {
    int t = blockIdx.x * blockDim.x + threadIdx.x;
    if (t < 2048) stats[t] = 0.f;
    if (t < NGRAPH * 256) accp[t] = 0.f;
    if (t < N) cnt[t] = 0;
    int i = t << 3;
    if (i >= total) return;
    f32x4 a = *(const f32x4*)(x + i);
    f32x4 b = *(const f32x4*)(x + i + 4);
    half8 r;
#pragma unroll
    for (int k = 0; k < 4; ++k) { r[k] = (_Float16)a[k]; r[k + 4] = (_Float16)b[k]; }
    *(half8*)(o + i) = r;
}

// ---------------------------------------------------------------- CSR build
__global__ void edge_count(const int* __restrict__ ei, int* __restrict__ cnt,
                           int* __restrict__ rank, int E) {
    int e = blockIdx.x * blockDim.x + threadIdx.x;
    if (e < E) rank[e] = atomicAdd(&cnt[ei[E + e]], 1);
}

__global__ void scan_p1(const int* __restrict__ cnt, int* __restrict__ part, int N) {
    __shared__ int lds[256];
    int idx = blockIdx.x * 256 + threadIdx.x;
    lds[threadIdx.x] = (idx < N) ? cnt[idx] : 0;
    __syncthreads();
    for (int d = 128; d > 0; d >>= 1) {
        if (threadIdx.x < d) lds[threadIdx.x] += lds[threadIdx.x + d];
        __syncthreads();
    }
    if (threadIdx.x == 0) part[blockIdx.x] = lds[0];
}

// block scan of partials + graph bounds (merged graph_bounds kernel)
__global__ void scan_p2(int* __restrict__ part, int* __restrict__ off, int N, int nb,
                        const int* __restrict__ batch, int* __restrict__ gstart) {
    __shared__ int lds[256];
    int t = threadIdx.x;
    int v = (t < nb) ? part[t] : 0;
    lds[t] = v;
    __syncthreads();
    for (int d = 1; d < 256; d <<= 1) {
        int a = (t >= d) ? lds[t - d] : 0;
        __syncthreads();
        lds[t] += a;
        __syncthreads();
    }
    if (t < nb) part[t] = lds[t] - v;
    if (t == nb - 1) off[N] = lds[t];
    if (t <= NGRAPH) {                       // graph bounds (batch is sorted)
        if (t == NGRAPH) gstart[t] = N;
        else {
            int lo = 0, hi = N;
            while (lo < hi) { int m = (lo + hi) >> 1; if (batch[m] < t) lo = m + 1; else hi = m; }
            gstart[t] = lo;
        }
    }
}

__global__ void scan_p3(const int* __restrict__ cnt, const int* __restrict__ part,
                        int* __restrict__ off, int N) {
    __shared__ int lds[256];
    int t = threadIdx.x;
    int idx = blockIdx.x * 256 + t;
    int v = (idx < N) ? cnt[idx] : 0;
    lds[t] = v;
    __syncthreads();
    for (int d = 1; d < 256; d <<= 1) {
        int a = (t >= d) ? lds[t - d] : 0;
        __syncthreads();
        lds[t] += a;
        __syncthreads();
    }
    if (idx < N) off[idx] = part[blockIdx.x] + lds[t] - v;
}

__global__ void edge_fill(const int* __restrict__ ei, const int* __restrict__ off,
                          const int* __restrict__ rank, int* __restrict__ csr_src, int E) {
    int e = blockIdx.x * blockDim.x + threadIdx.x;
    if (e >= E) return;
    csr_src[off[ei[E + e]] + rank[e]] = ei[e];
}

// ---------------------------------------------------------------- gathers
// (HBM/L3 random-read bound at ~185MB compulsory traffic — structural floor)
__global__ void gather0(const _Float16* __restrict__ x, const int* __restrict__ off,
                        const int* __restrict__ srcs, _Float16* __restrict__ out, int N) {
    int wid = (blockIdx.x << 2) + (threadIdx.x >> 6);
    if (wid >= N) return;
    int lane = threadIdx.x & 63;
    int q = lane >> 4;
    int fb = (lane & 15) << 3;
    const char* xb = (const char*)x;
    unsigned fb2 = (unsigned)fb << 1;
    float acc[8] = {0.f, 0.f, 0.f, 0.f, 0.f, 0.f, 0.f, 0.f};
    int end = off[wid + 1];
    int e = off[wid] + q;
    for (; e + 4 < end; e += 8) {
        half8 v0 = *(const half8*)(xb + (((unsigned)srcs[e] << 8) + fb2));
        half8 v1 = *(const half8*)(xb + (((unsigned)srcs[e + 4] << 8) + fb2));
        half8 p = v0 + v1;
#pragma unroll
        for (int k = 0; k < 8; ++k) acc[k] += (float)p[k];
    }
    if (e < end) {
        half8 v0 = *(const half8*)(xb + (((unsigned)srcs[e] << 8) + fb2));
#pragma unroll
        for (int k = 0; k < 8; ++k) acc[k] += (float)v0[k];
    }
    if (q == 0) {
        half8 v = *(const half8*)(xb + (((unsigned)wid << 8) + fb2));
#pragma unroll
        for (int k = 0; k < 8; ++k) acc[k] += (float)v[k];
    }
#pragma unroll
    for (int k = 0; k < 8; ++k) {
        acc[k] += __shfl_xor(acc[k], 16);
        acc[k] += __shfl_xor(acc[k], 32);
    }
    if (q == 0) {
        half8 o;
#pragma unroll
        for (int k = 0; k < 8; ++k) o[k] = (_Float16)acc[k];
        *(half8*)(out + (size_t)wid * 128 + fb) = o;
    }
}

// recurrent: BN coefs computed once per BLOCK into LDS (replaces bn_coef kernel),
// then BN affine + ReLU in packed fp16, pairwise pre-add, f32 accumulate.
__global__ void gather_fused(const _Float16* __restrict__ z, const int* __restrict__ off,
                             const int* __restrict__ srcs, const float* __restrict__ stats,
                             const float* __restrict__ gam, const float* __restrict__ bet,
                             _Float16* __restrict__ out, int N, float invN) {
    __shared__ _Float16 cs[512];             // sc[256] | tc[256]
    {
        int c = threadIdx.x;                 // block = 256 threads = 256 cols
        float mu = stats[c] * invN;
        float var = stats[256 + c] * invN - mu * mu;
        float s = gam[c] * rsqrtf(var + BN_EPS);
        cs[c] = (_Float16)s;
        cs[256 + c] = (_Float16)(bet[c] - mu * s);
    }
    __syncthreads();                         // before any early exit (divergence)
    int wid = (blockIdx.x << 2) + (threadIdx.x >> 6);
    if (wid >= N) return;
    int lane = threadIdx.x & 63;
    int hf = lane >> 5;
    int fb = (lane & 31) << 3;
    half8 sc8 = *(const half8*)(cs + fb);
    half8 tc8 = *(const half8*)(cs + 256 + fb);
    const half8 zero8 = {0, 0, 0, 0, 0, 0, 0, 0};
    const char* zb = (const char*)z;
    unsigned fb2 = (unsigned)fb << 1;
    float acc[8] = {0.f, 0.f, 0.f, 0.f, 0.f, 0.f, 0.f, 0.f};
    int end = off[wid + 1];
    int e = off[wid] + hf;
    for (; e + 6 < end; e += 8) {
        half8 v0 = *(const half8*)(zb + (((unsigned)srcs[e] << 9) + fb2));
        half8 v1 = *(const half8*)(zb + (((unsigned)srcs[e + 2] << 9) + fb2));
        half8 v2 = *(const half8*)(zb + (((unsigned)srcs[e + 4] << 9) + fb2));
        half8 v3 = *(const half8*)(zb + (((unsigned)srcs[e + 6] << 9) + fb2));
        half8 r0 = __builtin_elementwise_max(v0 * sc8 + tc8, zero8);
        half8 r1 = __builtin_elementwise_max(v1 * sc8 + tc8, zero8);
        half8 r2 = __builtin_elementwise_max(v2 * sc8 + tc8, zero8);
        half8 r3 = __builtin_elementwise_max(v3 * sc8 + tc8, zero8);
        half8 p01 = r0 + r1;
        half8 p23 = r2 + r3;
#pragma unroll
        for (int k = 0; k < 8; ++k)
            acc[k] += (float)p01[k] + (float)p23[k];
    }
    for (; e < end; e += 2) {
        half8 v0 = *(const half8*)(zb + (((unsigned)srcs[e] << 9) + fb2));
        half8 r0 = __builtin_elementwise_max(v0 * sc8 + tc8, zero8);
#pragma unroll
        for (int k = 0; k < 8; ++k) acc[k] += (float)r0[k];
    }
    if (hf == 0) {
        half8 v = *(const half8*)(zb + (((unsigned)wid << 9) + fb2));
        half8 r = __builtin_elementwise_max(v * sc8 + tc8, zero8);
#pragma unroll
        for (int k = 0; k < 8; ++k) acc[k] += (float)r[k];
    }
#pragma unroll
    for (int k = 0; k < 8; ++k) acc[k] += __shfl_xor(acc[k], 32);
    if (hf == 0) {
        half8 o;
#pragma unroll
        for (int k = 0; k < 8; ++k) o[k] = (_Float16)acc[k];
        *(half8*)(out + (size_t)wid * 256 + fb) = o;
    }
}

// ---------------------------------------------------------------- GEMM (fp16 MFMA)
// BN=256 full-width blocks (A read once), K-chunked swizzled weight staging,
// LDS-staged coalesced stores (round-8 structure, best verified GEMM).
template <int K, int WITH_STATS>
__global__ __launch_bounds__(512, 4) void gemm_kernel(
    const _Float16* __restrict__ A, const _Float16* __restrict__ BT,
    const float* __restrict__ bias, _Float16* __restrict__ Y,
    float* __restrict__ stats, int M) {
    extern __shared__ _Float16 blds[];       // region0: weights chunk / ostage
    float* sred = (float*)(blds + 17408);    // region1 @34816B: [2][8][256] f32
    const int tid = threadIdx.x;
    const int lane = tid & 63, wave = tid >> 6;
    const int i = lane & 15, g = lane >> 4;
    const int rowbase = blockIdx.x * 128 + wave * 16;
    const int arow = min(rowbase + i, M - 1);

    half8 afrag[K / 32];
#pragma unroll
    for (int s = 0; s < K / 32; ++s)
        afrag[s] = *(const half8*)(A + (size_t)arow * K + s * 32 + g * 8);

    f32x4 acc[16];
#pragma unroll
    for (int t = 0; t < 16; ++t) acc[t] = (f32x4){0.f, 0.f, 0.f, 0.f};

    const int scol = tid >> 1;
    const int shalf = (tid & 1) * 32;
    const int ssw = (scol & 7) << 3;
    const int swi = (i & 7) << 3;

#pragma unroll
    for (int kc = 0; kc < K / 64; ++kc) {
        if (kc) __syncthreads();
        {   // stage [256][64] chunk, XOR-swizzled
            const _Float16* src = BT + (size_t)scol * K + kc * 64 + shalf;
            _Float16* dst = blds + scol * 64;
#pragma unroll
            for (int c = 0; c < 32; c += 8)
                *(half8*)(dst + ((shalf + c) ^ ssw)) = *(const half8*)(src + c);
        }
        __syncthreads();
#pragma unroll
        for (int ks = 0; ks < 2; ++ks)
#pragma unroll
            for (int t = 0; t < 16; ++t) {
                half8 b = *(const half8*)(blds + (t * 16 + i) * 64 + ((ks * 32 + g * 8) ^ swi));
                acc[t] = __builtin_amdgcn_mfma_f32_16x16x32_f16(afrag[kc * 2 + ks], b, acc[t], 0, 0, 0);
            }
    }

    const int rg = g * 4;
    if (WITH_STATS) {
#pragma unroll
        for (int t = 0; t < 16; ++t) {
            int c = t * 16 + i;
            float bv = bias[c];
            float s1 = 0.f, s2 = 0.f;
#pragma unroll
            for (int j = 0; j < 4; ++j) {
                if (rowbase + rg + j < M) {
                    float v = acc[t][j] + bv;
                    s1 += v;
                    s2 += v * v;
                }
            }
            s1 += __shfl_xor(s1, 16); s1 += __shfl_xor(s1, 32);
            s2 += __shfl_xor(s2, 16); s2 += __shfl_xor(s2, 32);
            if (g == 0) {
                sred[wave * 256 + c] = s1;
                sred[2048 + wave * 256 + c] = s2;
            }
        }
    }
    __syncthreads();
    if (WITH_STATS) {
        int which = tid >> 8, c = tid & 255;
        float s = 0.f;
#pragma unroll
        for (int w = 0; w < 8; ++w) s += sred[which * 2048 + w * 256 + c];
        atomicAdd(&stats[which * 256 + c], s);
    }

    _Float16* ostage = blds;
#pragma unroll
    for (int ph = 0; ph < 2; ++ph) {
        if (ph) __syncthreads();
#pragma unroll
        for (int tt = 0; tt < 8; ++tt) {
            int t = ph * 8 + tt;
            int lc = tt * 16 + i;
            float bv = bias[t * 16 + i];
#pragma unroll
            for (int j = 0; j < 4; ++j) {
                float v = acc[t][j] + bv;
                if (WITH_STATS == 0) v = fmaxf(v, 0.f);
                ostage[(wave * 16 + rg + j) * 136 + lc] = (_Float16)v;
            }
        }
        __syncthreads();
#pragma unroll
        for (int k = 0; k < 4; ++k) {
            int ch = k * 512 + tid;
            int rl = ch >> 4, pc = (ch & 15) << 3;
            int r = blockIdx.x * 128 + rl;
            if (r < M)
                *(half8*)(Y + (size_t)r * 256 + ph * 128 + pc) =
                    *(const half8*)(ostage + rl * 136 + pc);
        }
    }
}

// ---------------------------------------------------------------- pooling
#define PCHUNK 256
// BN coefs computed per block (tid<256), fused affine+ReLU, segment atomics.
__global__ void pool_stage1(const _Float16* __restrict__ z, const int* __restrict__ batch,
                            const int* __restrict__ gstart, const float* __restrict__ stats,
                            const float* __restrict__ gam, const float* __restrict__ bet,
                            float* __restrict__ acc, int N, float invN) {
    __shared__ float lds[8 * 512];
    __shared__ float cs[512];                // sc[256] | tc[256]
    int tid = threadIdx.x;
    if (tid < 256) {
        int c = tid;
        float mu = stats[c] * invN;
        float var = stats[256 + c] * invN - mu * mu;
        float s = gam[c] * rsqrtf(var + BN_EPS);
        cs[c] = s;
        cs[256 + c] = bet[c] - mu * s;
    }
    __syncthreads();
    int c0 = blockIdx.x * PCHUNK;
    int cend = min(c0 + PCHUNK, N);
    int rowlane = tid >> 5;
    int fb = (tid & 31) << 3;
    float sc[8], tc[8];
#pragma unroll
    for (int k = 0; k < 8; ++k) { sc[k] = cs[fb + k]; tc[k] = cs[256 + fb + k]; }
    int segs = c0;
    while (segs < cend) {
        int g = batch[segs];
        int sege = min(gstart[g + 1], cend);
        float a[8] = {0.f, 0.f, 0.f, 0.f, 0.f, 0.f, 0.f, 0.f};
        for (int r = segs + rowlane; r < sege; r += 16) {
            half8 v = *(const half8*)(z + (size_t)r * 256 + fb);
#pragma unroll
            for (int k = 0; k < 8; ++k)
                a[k] += fmaxf(fmaf((float)v[k], sc[k], tc[k]), 0.f);
        }
#pragma unroll
        for (int k = 0; k < 8; ++k) lds[k * 512 + tid] = a[k];
        __syncthreads();
#pragma unroll
        for (int d = 8; d > 0; d >>= 1) {
            if (rowlane < d) {
#pragma unroll
                for (int k = 0; k < 8; ++k)
                    lds[k * 512 + tid] += lds[k * 512 + tid + d * 32];
            }
            __syncthreads();
        }
        if (rowlane == 0) {
#pragma unroll
            for (int k = 0; k < 8; ++k)
                atomicAdd(&acc[g * 256 + fb + k], lds[k * 512 + tid]);
        }
        __syncthreads();
        segs = sege;
    }
}

__global__ void pool_finalize(const float* __restrict__ acc, const int* __restrict__ gstart,
                              float* __restrict__ out) {
    int i = blockIdx.x * 256 + threadIdx.x;
    int g = i >> 8;
    int c = gstart[g + 1] - gstart[g];
    out[i] = acc[i] / (float)(c > 0 ? c : 1);
}

// ---------------------------------------------------------------- launch
extern "C" void kernel_launch(void* const* d_in, const int* in_sizes, int n_in,
                              void* d_out, int out_size, void* d_ws, size_t ws_size,
                              hipStream_t stream) {
    const float* x    = (const float*)d_in[0];
    const int*   ei   = (const int*)d_in[1];
    const int*   batch= (const int*)d_in[2];
    const float* w1_0 = (const float*)d_in[3];
    const float* b1_0 = (const float*)d_in[4];
    const float* w2_0 = (const float*)d_in[5];
    const float* b2_0 = (const float*)d_in[6];
    const float* g_0  = (const float*)d_in[7];
    const float* be_0 = (const float*)d_in[8];
    const float* w1_r = (const float*)d_in[9];
    const float* b1_r = (const float*)d_in[10];
    const float* w2_r = (const float*)d_in[11];
    const float* b2_r = (const float*)d_in[12];
    const float* g_r  = (const float*)d_in[13];
    const float* be_r = (const float*)d_in[14];

    const int N = in_sizes[0] / 128;   // 50000
    const int E = in_sizes[1] / 2;     // 800000

    char* p = (char*)d_ws;
    auto alloc = [&](size_t bytes) { char* r = p; p += (bytes + 255) & ~(size_t)255; return r; };
    float*    stats   = (float*)alloc(4 * 512 * sizeof(float));
    int*      part    = (int*)alloc(256 * sizeof(int));
    int*      off     = (int*)alloc((size_t)(N + 1) * sizeof(int));
    int*      cnt     = (int*)alloc((size_t)N * sizeof(int));
    int*      gstart  = (int*)alloc(65 * sizeof(int));
    float*    accp    = (float*)alloc(NGRAPH * 256 * sizeof(float));
    int*      rank    = (int*)alloc((size_t)E * sizeof(int));
    int*      csr_src = (int*)alloc((size_t)E * sizeof(int));
    _Float16* wT      = (_Float16*)alloc((size_t)491520 * sizeof(_Float16));
    _Float16* x16     = (_Float16*)alloc((size_t)N * 128 * sizeof(_Float16));
    _Float16* zin     = (_Float16*)alloc((size_t)N * 256 * sizeof(_Float16));
    _Float16* y       = (_Float16*)alloc((size_t)N * 256 * sizeof(_Float16));
    _Float16* z       = (_Float16*)alloc((size_t)N * 256 * sizeof(_Float16));

    PrepArgs pa;
    pa.src[0] = w1_0;  pa.dst[0] = wT;           pa.K[0] = 128;
    pa.src[1] = w2_0;  pa.dst[1] = wT + 32768;   pa.K[1] = 256;
    for (int i = 0; i < 3; ++i) {
        pa.src[2 + i] = w1_r + (size_t)i * 65536; pa.dst[2 + i] = wT + 98304 + (size_t)i * 65536; pa.K[2 + i] = 256;
        pa.src[5 + i] = w2_r + (size_t)i * 65536; pa.dst[5 + i] = wT + 294912 + (size_t)i * 65536; pa.K[5 + i] = 256;
    }
    prep_weights<<<dim3(256, 8), 256, 0, stream>>>(pa);
    cast_x<<<(N * 128 / 8 + 255) / 256, 256, 0, stream>>>(x, x16, N * 128, stats, cnt, accp, N);

    const int eb = (E + 255) / 256;
    const int nb = (N + 255) / 256;
    edge_count<<<eb, 256, 0, stream>>>(ei, cnt, rank, E);
    scan_p1<<<nb, 256, 0, stream>>>(cnt, part, N);
    scan_p2<<<1, 256, 0, stream>>>(part, off, N, nb, batch, gstart);
    scan_p3<<<nb, 256, 0, stream>>>(cnt, part, off, N);
    edge_fill<<<eb, 256, 0, stream>>>(ei, off, rank, csr_src, E);

    const int gwb = (N + 3) / 4;
    const int gemmg = (N + 127) / 128;
    const int ldsb = 51200;
    const float invN = 1.0f / (float)N;

    // ---- layer 0
    gather0<<<gwb, 256, 0, stream>>>(x16, off, csr_src, zin, N);
    gemm_kernel<128, 0><<<gemmg, 512, ldsb, stream>>>(zin, wT, b1_0, y, nullptr, N);
    gemm_kernel<256, 1><<<gemmg, 512, ldsb, stream>>>(y, wT + 32768, b2_0, z, stats, N);

    // ---- layers 1..3 (BN of previous layer fused into gather, coefs in-block)
    const float* cur_stats = stats;
    const float* cur_g = g_0;
    const float* cur_be = be_0;
    for (int i = 0; i < 3; ++i) {
        gather_fused<<<gwb, 256, 0, stream>>>(z, off, csr_src, cur_stats, cur_g, cur_be, zin, N, invN);
        gemm_kernel<256, 0><<<gemmg, 512, ldsb, stream>>>(
            zin, wT + 98304 + (size_t)i * 65536, b1_r + i * 256, y, nullptr, N);
        gemm_kernel<256, 1><<<gemmg, 512, ldsb, stream>>>(
            y, wT + 294912 + (size_t)i * 65536, b2_r + i * 256, z, stats + (i + 1) * 512, N);
        cur_stats = stats + (i + 1) * 512;
        cur_g = g_r + i * 256;
        cur_be = be_r + i * 256;
    }

    // ---- pool (BN of last layer fused, coefs in-block)
    pool_stage1<<<(N + PCHUNK - 1) / PCHUNK, 512, 0, stream>>>(
        z, batch, gstart, cur_stats, cur_g, cur_be, accp, N, invN);
    pool_finalize<<<NGRAPH, 256, 0, stream>>>(accp, gstart, (float*)d_out);
}